// Round 2
// baseline (20.963 us; speedup 1.0000x reference)
//
#include <hip/hip_runtime.h>

// BEV feature extractor: bilinear-sample (B,H,W,C) at B*N points, then
// regroup (B, num_point, sec, C) -> (B, sec, num_point*C).
// Fixed problem shape from setup_inputs():
//   B=4, H=W=180, C=512, N_PTS=2500, num_point=5 -> sec=500.
#define BB   4
#define HH   180
#define WW   180
#define CC   512
#define NPTS 2500
#define NUMPT 5
#define SEC  (NPTS / NUMPT)   // 500

typedef float f4 __attribute__((ext_vector_type(4)));

__global__ __launch_bounds__(128) void bev_extract_kernel(
    const float* __restrict__ bev,      // (B,H,W,C)
    const float* __restrict__ centers,  // (B,NPTS,2)
    float* __restrict__ out)            // (B,SEC,NUMPT*CC)
{
    const int g = blockIdx.x;           // global point id, 0 .. B*NPTS-1
    const int b = g / NPTS;
    const int n = g - b * NPTS;

    const float cx = centers[(size_t)g * 2 + 0];
    const float cy = centers[(size_t)g * 2 + 1];

    // Match reference numerics: (x - PC_START) / VOXEL / OUT_STRIDE (two divides)
    const float xs = (cx + 54.0f) / 0.075f / 8.0f;
    const float ys = (cy + 54.0f) / 0.075f / 8.0f;

    int x0 = (int)floorf(xs);
    int y0 = (int)floorf(ys);
    int x1 = x0 + 1;
    int y1 = y0 + 1;
    // clip BEFORE computing the float corners (matches reference)
    x0 = min(max(x0, 0), WW - 1);
    x1 = min(max(x1, 0), WW - 1);
    y0 = min(max(y0, 0), HH - 1);
    y1 = min(max(y1, 0), HH - 1);

    const float x0f = (float)x0, x1f = (float)x1;
    const float y0f = (float)y0, y1f = (float)y1;
    const float wa = (x1f - xs) * (y1f - ys);
    const float wb = (x1f - xs) * (ys - y0f);
    const float wc = (xs - x0f) * (y1f - ys);
    const float wd = (xs - x0f) * (ys - y0f);

    const f4* base = (const f4*)(bev + (size_t)b * HH * WW * CC);
    const f4* pa = base + (size_t)(y0 * WW + x0) * (CC / 4);
    const f4* pb = base + (size_t)(y1 * WW + x0) * (CC / 4);
    const f4* pc = base + (size_t)(y0 * WW + x1) * (CC / 4);
    const f4* pd = base + (size_t)(y1 * WW + x1) * (CC / 4);

    // output regroup: point n -> (p = n/SEC, s = n%SEC); out[b][s][p*CC + c]
    const int p = n / SEC;
    const int s = n - p * SEC;
    f4* po = (f4*)(out + ((size_t)(b * SEC + s) * (NUMPT * CC) + p * CC));

    const int c = threadIdx.x;          // float4 index, 0..127 (CC/4 = 128)
    const f4 A  = pa[c];
    const f4 Bv = pb[c];
    const f4 Cv = pc[c];
    const f4 D  = pd[c];

    const f4 r = A * wa + Bv * wb + Cv * wc + D * wd;
    // Nontemporal: output is written once, never re-read by this kernel —
    // keep it from evicting gathered bev rows out of L2/L3 across replays.
    __builtin_nontemporal_store(r, po + c);
}

extern "C" void kernel_launch(void* const* d_in, const int* in_sizes, int n_in,
                              void* d_out, int out_size, void* d_ws, size_t ws_size,
                              hipStream_t stream) {
    const float* bev     = (const float*)d_in[0];
    const float* centers = (const float*)d_in[1];
    float* out = (float*)d_out;

    dim3 grid(BB * NPTS);   // 10000 blocks, one per point
    dim3 block(CC / 4);     // 128 threads, one float4 each
    bev_extract_kernel<<<grid, block, 0, stream>>>(bev, centers, out);
}

// Round 3
// 20.390 us; speedup vs baseline: 1.0281x; 1.0281x over previous
//
#include <hip/hip_runtime.h>

// BEV feature extractor: bilinear-sample (B,H,W,C) at B*N points, then
// regroup (B, num_point, sec, C) -> (B, sec, num_point*C).
// Fixed problem shape from setup_inputs():
//   B=4, H=W=180, C=512, N_PTS=2500, num_point=5 -> sec=500.
//
// R3 structure: one block per OUTPUT ROW (b, s). The 5 points that feed
// this row are n = p*SEC + s, p=0..4. Block = 5 sub-groups x 128 threads;
// each sub-group gathers one point's 4 bev rows and writes its 2 KB slice.
// The block's combined write is one contiguous 10 KB burst.
#define BB   4
#define HH   180
#define WW   180
#define CC   512
#define NPTS 2500
#define NUMPT 5
#define SEC  (NPTS / NUMPT)   // 500

typedef float f4 __attribute__((ext_vector_type(4)));

__global__ __launch_bounds__(NUMPT * CC / 4) void bev_extract_kernel(
    const float* __restrict__ bev,      // (B,H,W,C)
    const float* __restrict__ centers,  // (B,NPTS,2)
    float* __restrict__ out)            // (B,SEC,NUMPT*CC)
{
    const int sb = blockIdx.x;          // output row id, 0 .. B*SEC-1
    const int b  = sb / SEC;
    const int s  = sb - b * SEC;

    const int p = threadIdx.x >> 7;     // 0..4  (wave-uniform: 2 waves per p)
    const int c = threadIdx.x & 127;    // float4 index within the 2 KB slice

    const int n = p * SEC + s;          // point index within batch
    const int g = b * NPTS + n;         // global point id

    const float cx = centers[(size_t)g * 2 + 0];
    const float cy = centers[(size_t)g * 2 + 1];

    // Match reference numerics: (x - PC_START) / VOXEL / OUT_STRIDE (two divides)
    const float xs = (cx + 54.0f) / 0.075f / 8.0f;
    const float ys = (cy + 54.0f) / 0.075f / 8.0f;

    int x0 = (int)floorf(xs);
    int y0 = (int)floorf(ys);
    int x1 = x0 + 1;
    int y1 = y0 + 1;
    // clip BEFORE computing the float corners (matches reference)
    x0 = min(max(x0, 0), WW - 1);
    x1 = min(max(x1, 0), WW - 1);
    y0 = min(max(y0, 0), HH - 1);
    y1 = min(max(y1, 0), HH - 1);

    const float x0f = (float)x0, x1f = (float)x1;
    const float y0f = (float)y0, y1f = (float)y1;
    const float wa = (x1f - xs) * (y1f - ys);
    const float wb = (x1f - xs) * (ys - y0f);
    const float wc = (xs - x0f) * (y1f - ys);
    const float wd = (xs - x0f) * (ys - y0f);

    const f4* base = (const f4*)(bev + (size_t)b * HH * WW * CC);
    const f4* pa = base + (size_t)(y0 * WW + x0) * (CC / 4);
    const f4* pb = base + (size_t)(y1 * WW + x0) * (CC / 4);
    const f4* pc = base + (size_t)(y0 * WW + x1) * (CC / 4);
    const f4* pd = base + (size_t)(y1 * WW + x1) * (CC / 4);

    const f4 A  = pa[c];
    const f4 Bv = pb[c];
    const f4 Cv = pc[c];
    const f4 D  = pd[c];

    const f4 r = A * wa + Bv * wb + Cv * wc + D * wd;

    // out[b][s][p*CC + 4c] — across the block, threadIdx.x maps exactly to
    // one contiguous 10 KB output row.
    f4* po = (f4*)out + (size_t)sb * (NUMPT * CC / 4) + threadIdx.x;
    __builtin_nontemporal_store(r, po);
}

extern "C" void kernel_launch(void* const* d_in, const int* in_sizes, int n_in,
                              void* d_out, int out_size, void* d_ws, size_t ws_size,
                              hipStream_t stream) {
    const float* bev     = (const float*)d_in[0];
    const float* centers = (const float*)d_in[1];
    float* out = (float*)d_out;

    dim3 grid(BB * SEC);            // 2000 blocks, one per output row
    dim3 block(NUMPT * CC / 4);     // 640 threads: 5 points x 128 lanes
    bev_extract_kernel<<<grid, block, 0, stream>>>(bev, centers, out);
}